// Round 3
// baseline (19208.325 us; speedup 1.0000x reference)
//
#include <hip/hip_runtime.h>

#define TT   2048
#define NB   32
#define NI   512
#define NHID 512
#define NWG  32
#define KSL  16   // h-columns owned per workgroup

typedef float    f32x4 __attribute__((ext_vector_type(4)));
typedef float    f32x2 __attribute__((ext_vector_type(2)));
typedef _Float16 f16x8 __attribute__((ext_vector_type(8)));

__device__ __forceinline__ f16x8 pack8(f32x4 a, f32x4 b) {
    f16x8 r;
    r[0] = (_Float16)a[0]; r[1] = (_Float16)a[1]; r[2] = (_Float16)a[2]; r[3] = (_Float16)a[3];
    r[4] = (_Float16)b[0]; r[5] = (_Float16)b[1]; r[6] = (_Float16)b[2]; r[7] = (_Float16)b[3];
    return r;
}

extern "C" __global__ void init_flags_k(unsigned int* flags) {
    if (threadIdx.x < NWG) flags[threadIdx.x] = 0u;
}

// Persistent GRU kernel: 32 WGs x 256 threads, WG w owns h-columns [w*16, w*16+16).
// Waves 0,1: hidden-side gh (critical path). Waves 2,3: input-side gi + dense.
// fp16 MFMA operands (8x finer than bf16, same rate), f32 accumulate, f32 master h.
// h broadcast double-buffered by step parity to close the overwrite window.
extern "C" __global__ void __launch_bounds__(256, 1)
gru_persist(const float* __restrict__ X, const float* __restrict__ h0,
            const float* __restrict__ Wih, const float* __restrict__ Whh,
            const float* __restrict__ bih, const float* __restrict__ bhh,
            const float* __restrict__ Wd,  const float* __restrict__ bd,
            float* __restrict__ out, unsigned int* __restrict__ flags,
            _Float16* __restrict__ hb0, _Float16* __restrict__ hb1)
{
    // C tiles: slots 0..2 = gh(r,z,n), 3..5 = gi(r,z,n), 6 = dense. [slot][b][kl]
    __shared__ float C_lds[7][NB][KSL];
    __shared__ float h_lds[NB][KSL];       // f32 master copy of own h slice
    __shared__ float bias_lds[7][KSL];

    const int w    = blockIdx.x;
    const int ks   = w * KSL;
    const int tid  = threadIdx.x;
    const int lane = tid & 63;
    const int wv   = tid >> 6;
    const int bt   = wv & 1;    // batch tile (rows bt*16 .. +16)
    const int jg   = wv >> 1;   // 0 = hidden side, 1 = input side
    const int r15  = lane & 15;
    const int g4   = lane >> 4;

    // ---- one-time init: biases + own h slice into LDS
    if (tid < KSL) {
        int k = ks + tid;
        bias_lds[0][tid] = bhh[k];
        bias_lds[1][tid] = bhh[512 + k];
        bias_lds[2][tid] = bhh[1024 + k];
        bias_lds[3][tid] = bih[k];
        bias_lds[4][tid] = bih[512 + k];
        bias_lds[5][tid] = bih[1024 + k];
        bias_lds[6][tid] = bd[k];
    }
    {
        int idx = tid * 2;
        int b = idx >> 4, kl = idx & 15;
        f32x2 hv = *(const f32x2*)(h0 + (size_t)b * NHID + ks + kl);
        h_lds[b][kl]     = hv[0];
        h_lds[b][kl + 1] = hv[1];
    }

    // ---- one-time: weight A-fragments into registers (fp16), fragment layout:
    // A[q][kc]: lane holds W[row_base + (lane&15)][kc*32 + (lane>>4)*8 + e], e=0..7
    f16x8 A[4][16];
    {
        const float* m0 = (jg == 0) ? Whh : Wih;
        #pragma unroll
        for (int q = 0; q < 4; ++q) {
            const float* src;
            if (q < 3) src = m0 + (size_t)(q * 512 + ks + r15) * NI;
            else       src = (jg == 0) ? (m0 + (size_t)(1024 + ks + r15) * NI)   // dup (unused)
                                       : (Wd + (size_t)(ks + r15) * NI);
            #pragma unroll
            for (int kc = 0; kc < 16; ++kc) {
                const f32x4* p = (const f32x4*)(src + kc * 32 + g4 * 8);
                A[q][kc] = pack8(p[0], p[1]);
            }
        }
    }
    __syncthreads();

    const float* Xrow  = X  + (size_t)(bt * 16 + r15) * NI;
    const float* h0row = h0 + (size_t)(bt * 16 + r15) * NHID;
    const size_t hoff  = (size_t)(bt * 16 + r15) * NHID;

    #pragma unroll 1
    for (int t = 0; t < TT; ++t) {
        // ---- Phase A: input-side projections for step t (waves 2,3) — off critical path
        if (jg == 1) {
            const float* xp = Xrow + (size_t)t * (NB * NI);
            f16x8 Bf[16];
            #pragma unroll
            for (int kc = 0; kc < 16; ++kc) {
                const f32x4* p = (const f32x4*)(xp + kc * 32 + g4 * 8);
                Bf[kc] = pack8(p[0], p[1]);
            }
            f32x4 acc[4];
            #pragma unroll
            for (int q = 0; q < 4; ++q) acc[q] = (f32x4){0.f, 0.f, 0.f, 0.f};
            #pragma unroll
            for (int kc = 0; kc < 16; ++kc) {
                #pragma unroll
                for (int q = 0; q < 4; ++q)
                    acc[q] = __builtin_amdgcn_mfma_f32_16x16x32_f16(A[q][kc], Bf[kc], acc[q], 0, 0, 0);
            }
            #pragma unroll
            for (int q = 0; q < 4; ++q)
                *(f32x4*)&C_lds[3 + q][bt * 16 + r15][g4 * 4] = acc[q];
        }

        // ---- Phase B: wait for all h_t slices (skip at t==0: h comes from input)
        if (t > 0 && tid < NWG) {
            while (__hip_atomic_load(&flags[tid], __ATOMIC_RELAXED,
                                     __HIP_MEMORY_SCOPE_AGENT) < (unsigned)t) { }
        }
        __syncthreads();
        if (t > 0) __builtin_amdgcn_fence(__ATOMIC_ACQUIRE, "agent");

        // ---- Phase C: hidden-side gh (waves 0,1) — the critical path
        if (jg == 0) {
            f16x8 Bf[16];
            if (t == 0) {
                #pragma unroll
                for (int kc = 0; kc < 16; ++kc) {
                    const f32x4* p = (const f32x4*)(h0row + kc * 32 + g4 * 8);
                    Bf[kc] = pack8(p[0], p[1]);
                }
            } else {
                const _Float16* hrow = ((t & 1) ? hb1 : hb0) + hoff;
                #pragma unroll
                for (int kc = 0; kc < 16; ++kc)
                    Bf[kc] = *(const f16x8*)(hrow + kc * 32 + g4 * 8);
            }
            f32x4 acc[3];
            #pragma unroll
            for (int q = 0; q < 3; ++q) acc[q] = (f32x4){0.f, 0.f, 0.f, 0.f};
            #pragma unroll
            for (int kc = 0; kc < 16; ++kc) {
                #pragma unroll
                for (int q = 0; q < 3; ++q)
                    acc[q] = __builtin_amdgcn_mfma_f32_16x16x32_f16(A[q][kc], Bf[kc], acc[q], 0, 0, 0);
            }
            #pragma unroll
            for (int q = 0; q < 3; ++q)
                *(f32x4*)&C_lds[q][bt * 16 + r15][g4 * 4] = acc[q];
        }
        __syncthreads();

        // ---- Phase E: fused gates (f32), h update, output write
        {
            int idx = tid * 2;
            int b = idx >> 4, kl = idx & 15;
            float hn2[2], o2[2];
            #pragma unroll
            for (int e = 0; e < 2; ++e) {
                int k = kl + e;
                float ghr = C_lds[0][b][k] + bias_lds[0][k];
                float ghz = C_lds[1][b][k] + bias_lds[1][k];
                float ghn = C_lds[2][b][k] + bias_lds[2][k];
                float gir = C_lds[3][b][k] + bias_lds[3][k];
                float giz = C_lds[4][b][k] + bias_lds[4][k];
                float gin = C_lds[5][b][k] + bias_lds[5][k];
                float dns = C_lds[6][b][k] + bias_lds[6][k];
                float rr = 1.f / (1.f + __expf(-(gir + ghr)));
                float zz = 1.f / (1.f + __expf(-(giz + ghz)));
                float aa = gin + rr * ghn;
                float nn = 1.f - 2.f / (__expf(2.f * aa) + 1.f);   // tanh(aa)
                float hold = h_lds[b][k];
                float hn = (1.f - zz) * nn + zz * hold;
                h_lds[b][k] = hn;
                hn2[e] = hn;
                o2[e] = hn + dns;
            }
            // fp16 broadcast copy of h_{t+1} into parity buffer (t+1)&1:
            // agent-scope atomic store -> write-through to the coherence point.
            _Float16* hw = (((t + 1) & 1) ? hb1 : hb0);
            union { _Float16 hh[2]; unsigned int u; } cv;
            cv.hh[0] = (_Float16)hn2[0]; cv.hh[1] = (_Float16)hn2[1];
            __hip_atomic_store((unsigned int*)(hw + (size_t)b * NHID + ks + kl), cv.u,
                               __ATOMIC_RELAXED, __HIP_MEMORY_SCOPE_AGENT);
            f32x2 ov = { o2[0], o2[1] };
            *(f32x2*)&out[(size_t)t * (NB * NHID) + (size_t)b * NHID + ks + kl] = ov;
        }
        __syncthreads();   // drains vmem stores of all threads before publish

        // ---- Phase F: publish h_{t+1}
        if (tid == 0) {
            __builtin_amdgcn_fence(__ATOMIC_RELEASE, "agent");
            __hip_atomic_store(&flags[w], (unsigned)(t + 1), __ATOMIC_RELEASE,
                               __HIP_MEMORY_SCOPE_AGENT);
        }
    }

    // ---- h_last output
    {
        int idx = tid * 2;
        int b = idx >> 4, kl = idx & 15;
        float* hl = out + (size_t)TT * NB * NHID;
        f32x2 hv = { h_lds[b][kl], h_lds[b][kl + 1] };
        *(f32x2*)&hl[(size_t)b * NHID + ks + kl] = hv;
    }
}

extern "C" void kernel_launch(void* const* d_in, const int* in_sizes, int n_in,
                              void* d_out, int out_size, void* d_ws, size_t ws_size,
                              hipStream_t stream) {
    const float* X   = (const float*)d_in[0];
    const float* h0  = (const float*)d_in[1];
    const float* Wih = (const float*)d_in[2];
    const float* Whh = (const float*)d_in[3];
    const float* bih = (const float*)d_in[4];
    const float* bhh = (const float*)d_in[5];
    const float* Wd  = (const float*)d_in[6];
    const float* bd  = (const float*)d_in[7];
    float* out = (float*)d_out;

    unsigned int* flags = (unsigned int*)d_ws;                      // 32 words
    _Float16* hb0 = (_Float16*)((char*)d_ws + 1024);                // 32x512 fp16 = 32KB
    _Float16* hb1 = (_Float16*)((char*)d_ws + 1024 + 32768);        // 32x512 fp16 = 32KB

    init_flags_k<<<dim3(1), dim3(64), 0, stream>>>(flags);

    gru_persist<<<dim3(NWG), dim3(256), 0, stream>>>(
        X, h0, Wih, Whh, bih, bhh, Wd, bd, out, flags, hb0, hb1);
}

// Round 4
// 18193.295 us; speedup vs baseline: 1.0558x; 1.0558x over previous
//
#include <hip/hip_runtime.h>

#define TT   2048
#define NB   32
#define NI   512
#define NHID 512
#define NWG  32
#define KSL  16   // h-columns owned per workgroup

typedef float    f32x4 __attribute__((ext_vector_type(4)));
typedef float    f32x2 __attribute__((ext_vector_type(2)));
typedef _Float16 f16x8 __attribute__((ext_vector_type(8)));

__device__ __forceinline__ f16x8 pack8(f32x4 a, f32x4 b) {
    f16x8 r;
    r[0] = (_Float16)a[0]; r[1] = (_Float16)a[1]; r[2] = (_Float16)a[2]; r[3] = (_Float16)a[3];
    r[4] = (_Float16)b[0]; r[5] = (_Float16)b[1]; r[6] = (_Float16)b[2]; r[7] = (_Float16)b[3];
    return r;
}

extern "C" __global__ void init_flags_k(unsigned int* flags) {
    if (threadIdx.x < NWG) flags[threadIdx.x] = 0u;
}

// Persistent GRU kernel: 32 WGs x 256 threads, WG w owns h-columns [w*16, w*16+16).
// Waves 0,1: hidden-side gh (critical path). Waves 2,3: input-side gi + dense.
// FENCELESS handshake: h broadcast uses agent-scope atomic (cache-bypass) stores
// AND loads, so no acquire/release fences (no per-step L2 inv/writeback).
// Producer order: h atomic stores -> s_waitcnt vmcnt(0) -> barrier -> relaxed flag.
// out[t] stores deferred past the flag publish (drain during next step's wait).
extern "C" __global__ void __launch_bounds__(256, 1)
gru_persist(const float* __restrict__ X, const float* __restrict__ h0,
            const float* __restrict__ Wih, const float* __restrict__ Whh,
            const float* __restrict__ bih, const float* __restrict__ bhh,
            const float* __restrict__ Wd,  const float* __restrict__ bd,
            float* __restrict__ out, unsigned int* __restrict__ flags,
            _Float16* __restrict__ hb0, _Float16* __restrict__ hb1)
{
    // C tiles: slots 0..2 = gh(r,z,n), 3..5 = gi(r,z,n), 6 = dense. [slot][b][kl]
    __shared__ float C_lds[7][NB][KSL];
    __shared__ float h_lds[NB][KSL];       // f32 master copy of own h slice
    __shared__ float bias_lds[7][KSL];

    const int w    = blockIdx.x;
    const int ks   = w * KSL;
    const int tid  = threadIdx.x;
    const int lane = tid & 63;
    const int wv   = tid >> 6;
    const int bt   = wv & 1;    // batch tile (rows bt*16 .. +16)
    const int jg   = wv >> 1;   // 0 = hidden side, 1 = input side
    const int r15  = lane & 15;
    const int g4   = lane >> 4;

    // ---- one-time init: biases + own h slice into LDS
    if (tid < KSL) {
        int k = ks + tid;
        bias_lds[0][tid] = bhh[k];
        bias_lds[1][tid] = bhh[512 + k];
        bias_lds[2][tid] = bhh[1024 + k];
        bias_lds[3][tid] = bih[k];
        bias_lds[4][tid] = bih[512 + k];
        bias_lds[5][tid] = bih[1024 + k];
        bias_lds[6][tid] = bd[k];
    }
    {
        int idx = tid * 2;
        int b = idx >> 4, kl = idx & 15;
        f32x2 hv = *(const f32x2*)(h0 + (size_t)b * NHID + ks + kl);
        h_lds[b][kl]     = hv[0];
        h_lds[b][kl + 1] = hv[1];
    }

    // ---- one-time: weight A-fragments into registers (fp16), fragment layout:
    // A[q][kc]: lane holds W[row_base + (lane&15)][kc*32 + (lane>>4)*8 + e], e=0..7
    f16x8 A[4][16];
    {
        const float* m0 = (jg == 0) ? Whh : Wih;
        #pragma unroll
        for (int q = 0; q < 4; ++q) {
            const float* src;
            if (q < 3) src = m0 + (size_t)(q * 512 + ks + r15) * NI;
            else       src = (jg == 0) ? (m0 + (size_t)(1024 + ks + r15) * NI)   // dup (unused)
                                       : (Wd + (size_t)(ks + r15) * NI);
            #pragma unroll
            for (int kc = 0; kc < 16; ++kc) {
                const f32x4* p = (const f32x4*)(src + kc * 32 + g4 * 8);
                A[q][kc] = pack8(p[0], p[1]);
            }
        }
    }
    __syncthreads();

    const float* Xrow  = X  + (size_t)(bt * 16 + r15) * NI;
    const float* h0row = h0 + (size_t)(bt * 16 + r15) * NHID;
    const size_t hoff  = (size_t)(bt * 16 + r15) * NHID;

    #pragma unroll 1
    for (int t = 0; t < TT; ++t) {
        // ---- Phase A: input-side projections for step t (waves 2,3) — off critical path
        if (jg == 1) {
            const float* xp = Xrow + (size_t)t * (NB * NI);
            f16x8 Bf[16];
            #pragma unroll
            for (int kc = 0; kc < 16; ++kc) {
                const f32x4* p = (const f32x4*)(xp + kc * 32 + g4 * 8);
                Bf[kc] = pack8(p[0], p[1]);
            }
            f32x4 acc[4];
            #pragma unroll
            for (int q = 0; q < 4; ++q) acc[q] = (f32x4){0.f, 0.f, 0.f, 0.f};
            #pragma unroll
            for (int kc = 0; kc < 16; ++kc) {
                #pragma unroll
                for (int q = 0; q < 4; ++q)
                    acc[q] = __builtin_amdgcn_mfma_f32_16x16x32_f16(A[q][kc], Bf[kc], acc[q], 0, 0, 0);
            }
            #pragma unroll
            for (int q = 0; q < 4; ++q)
                *(f32x4*)&C_lds[3 + q][bt * 16 + r15][g4 * 4] = acc[q];
        }

        // ---- Phase B: wait for all h_t slices (skip at t==0: h comes from input).
        // No acquire fence: h is read below with cache-bypassing atomic loads.
        if (t > 0 && tid < NWG) {
            while (__hip_atomic_load(&flags[tid], __ATOMIC_RELAXED,
                                     __HIP_MEMORY_SCOPE_AGENT) < (unsigned)t) { }
        }
        __syncthreads();

        // ---- Phase C: hidden-side gh (waves 0,1) — the critical path
        if (jg == 0) {
            f16x8 Bf[16];
            if (t == 0) {
                #pragma unroll
                for (int kc = 0; kc < 16; ++kc) {
                    const f32x4* p = (const f32x4*)(h0row + kc * 32 + g4 * 8);
                    Bf[kc] = pack8(p[0], p[1]);
                }
            } else {
                const _Float16* hrow = ((t & 1) ? hb1 : hb0) + hoff;
                #pragma unroll
                for (int kc = 0; kc < 16; ++kc) {
                    union { unsigned long long u[2]; f16x8 v; } cv;
                    const unsigned long long* p =
                        (const unsigned long long*)(hrow + kc * 32 + g4 * 8);
                    cv.u[0] = __hip_atomic_load(p,     __ATOMIC_RELAXED, __HIP_MEMORY_SCOPE_AGENT);
                    cv.u[1] = __hip_atomic_load(p + 1, __ATOMIC_RELAXED, __HIP_MEMORY_SCOPE_AGENT);
                    Bf[kc] = cv.v;
                }
            }
            f32x4 acc[3];
            #pragma unroll
            for (int q = 0; q < 3; ++q) acc[q] = (f32x4){0.f, 0.f, 0.f, 0.f};
            #pragma unroll
            for (int kc = 0; kc < 16; ++kc) {
                #pragma unroll
                for (int q = 0; q < 3; ++q)
                    acc[q] = __builtin_amdgcn_mfma_f32_16x16x32_f16(A[q][kc], Bf[kc], acc[q], 0, 0, 0);
            }
            #pragma unroll
            for (int q = 0; q < 3; ++q)
                *(f32x4*)&C_lds[q][bt * 16 + r15][g4 * 4] = acc[q];
        }
        __syncthreads();

        // ---- Phase E: fused gates (f32), h update
        int   idx = tid * 2;
        int   b   = idx >> 4, kl = idx & 15;
        float o2[2];
        {
            float hn2[2];
            #pragma unroll
            for (int e = 0; e < 2; ++e) {
                int k = kl + e;
                float ghr = C_lds[0][b][k] + bias_lds[0][k];
                float ghz = C_lds[1][b][k] + bias_lds[1][k];
                float ghn = C_lds[2][b][k] + bias_lds[2][k];
                float gir = C_lds[3][b][k] + bias_lds[3][k];
                float giz = C_lds[4][b][k] + bias_lds[4][k];
                float gin = C_lds[5][b][k] + bias_lds[5][k];
                float dns = C_lds[6][b][k] + bias_lds[6][k];
                float rr = 1.f / (1.f + __expf(-(gir + ghr)));
                float zz = 1.f / (1.f + __expf(-(giz + ghz)));
                float aa = gin + rr * ghn;
                float nn = 1.f - 2.f / (__expf(2.f * aa) + 1.f);   // tanh(aa)
                float hold = h_lds[b][k];
                float hn = (1.f - zz) * nn + zz * hold;
                h_lds[b][k] = hn;
                hn2[e] = hn;
                o2[e] = hn + dns;
            }
            // fp16 broadcast copy of h_{t+1} into parity buffer (t+1)&1:
            // agent-scope atomic store -> write-through to the coherence point.
            _Float16* hw = (((t + 1) & 1) ? hb1 : hb0);
            union { _Float16 hh[2]; unsigned int u; } cv;
            cv.hh[0] = (_Float16)hn2[0]; cv.hh[1] = (_Float16)hn2[1];
            __hip_atomic_store((unsigned int*)(hw + (size_t)b * NHID + ks + kl), cv.u,
                               __ATOMIC_RELAXED, __HIP_MEMORY_SCOPE_AGENT);
        }
        // Per-wave: our h store has reached the coherence point before the barrier.
        asm volatile("s_waitcnt vmcnt(0)" ::: "memory");
        __syncthreads();

        // ---- Phase F: publish h_{t+1} (relaxed — h already at coherence point)
        if (tid == 0) {
            __hip_atomic_store(&flags[w], (unsigned)(t + 1), __ATOMIC_RELAXED,
                               __HIP_MEMORY_SCOPE_AGENT);
        }

        // ---- deferred output write (drains during next step's wait)
        {
            f32x2 ov = { o2[0], o2[1] };
            *(f32x2*)&out[(size_t)t * (NB * NHID) + (size_t)b * NHID + ks + kl] = ov;
        }
    }

    // ---- h_last output
    {
        int idx = tid * 2;
        int b = idx >> 4, kl = idx & 15;
        float* hl = out + (size_t)TT * NB * NHID;
        f32x2 hv = { h_lds[b][kl], h_lds[b][kl + 1] };
        *(f32x2*)&hl[(size_t)b * NHID + ks + kl] = hv;
    }
}

extern "C" void kernel_launch(void* const* d_in, const int* in_sizes, int n_in,
                              void* d_out, int out_size, void* d_ws, size_t ws_size,
                              hipStream_t stream) {
    const float* X   = (const float*)d_in[0];
    const float* h0  = (const float*)d_in[1];
    const float* Wih = (const float*)d_in[2];
    const float* Whh = (const float*)d_in[3];
    const float* bih = (const float*)d_in[4];
    const float* bhh = (const float*)d_in[5];
    const float* Wd  = (const float*)d_in[6];
    const float* bd  = (const float*)d_in[7];
    float* out = (float*)d_out;

    unsigned int* flags = (unsigned int*)d_ws;                      // 32 words
    _Float16* hb0 = (_Float16*)((char*)d_ws + 1024);                // 32x512 fp16 = 32KB
    _Float16* hb1 = (_Float16*)((char*)d_ws + 1024 + 32768);        // 32x512 fp16 = 32KB

    init_flags_k<<<dim3(1), dim3(64), 0, stream>>>(flags);

    gru_persist<<<dim3(NWG), dim3(256), 0, stream>>>(
        X, h0, Wih, Whh, bih, bhh, Wd, bd, out, flags, hb0, hb1);
}